// Round 1
// 316.049 us; speedup vs baseline: 1.0029x; 1.0029x over previous
//
#include <hip/hip_runtime.h>

static constexpr int   N_DIM        = 64;
static constexpr float HALF_LOG_2PI = 0.9189385332046727f;
static constexpr float CLIP_RATIO   = 0.2f;
static constexpr float DUAL_CLIP    = 5.0f;
static constexpr int   GRID         = 2048;   // main-kernel blocks
static constexpr float ENT_CONST    = (float)N_DIM * (0.5f + HALF_LOG_2PI); // per-row entropy const
static constexpr float ENT_C16      = ENT_CONST / 16.0f;  // spread over 16 lanes

// Per-lane partials for one 4-row set (lane group of 16 covers one row's 64
// dims as 4 elems/lane). en = sum log(sigma_new) partial; d = partial of
// (logp_new - logp_old) (HALF_LOG_2PI cancels).
// Trans-op diet: log of the 4-element product (sigma in [0.5,1.5] -> product
// in [0.0625, 5.06], no over/underflow) replaces 4 logs with 3 muls + 1 log.
__device__ __forceinline__ void ppo_set(const float4& mn, const float4& sn,
                                        const float4& mo, const float4& so,
                                        const float4& a,
                                        float& en_out, float& d_out)
{
    float qn = 0.f, qo = 0.f;
    float pn = 1.f, po = 1.f;
#define PPO_COMP(c) {                                        \
        float rn = __builtin_amdgcn_rcpf(sn.c);              \
        float zn = (a.c - mn.c) * rn;  qn += zn * zn;        \
        float ro = __builtin_amdgcn_rcpf(so.c);              \
        float zo = (a.c - mo.c) * ro;  qo += zo * zo;        \
        pn *= sn.c;  po *= so.c; }
    PPO_COMP(x) PPO_COMP(y) PPO_COMP(z) PPO_COMP(w)
#undef PPO_COMP
    const float en = __logf(pn);
    const float eo = __logf(po);
    en_out = en;
    d_out  = 0.5f * (qo - qn) + (eo - en);   // pn - po, per-lane partial
}

// Reduction + scalar tail for one set. accK/accE take per-lane partials
// (pre-reduce, linear). Only d crosses lanes (feeds exp). Tail runs
// redundantly on all 16 lanes of a row group (exact 16x, scaled 1/16 later).
__device__ __forceinline__ void ppo_tail(float en, float d, float w, float ad,
                                         float& accP, float& accE,
                                         float& accK, float& accC)
{
    accK -= d;                       // approx_kl partial (pre-reduce)
    accE += w * (en + ENT_C16);      // entropy partial
#pragma unroll
    for (int m = 1; m < 16; m <<= 1) d += __shfl_xor(d, m, 16);
    const float ratio = __expf(d);
    const float rc = fminf(fmaxf(ratio, 1.f - CLIP_RATIO), 1.f + CLIP_RATIO);
    float cl = fminf(ratio * ad, rc * ad);
    cl = fmaxf(cl, DUAL_CLIP * ad);
    accP += cl * w;
    accC += (fabsf(ratio - 1.f) > CLIP_RATIO) ? 1.f : 0.f;
}

// ---------------------------------------------------------------------------
// Main kernel. Explicit depth-1 software pipeline: two named register
// buffers (A/B) of one 4-row set each (5 float4 loads = 20 VGPR payload).
// The next set's loads are ISSUED before the current set's compute, so each
// wave keeps ~5 vector loads in flight continuously (the previous version's
// 40-VGPR allocation forced the compiler to drain vmcnt between bursts —
// latency-bound at 2.9 TB/s delivered).
// __launch_bounds__(256, 4): budget <=128 VGPR so regalloc does not
// pressure-serialize the load clusters; 4 waves/SIMD x 5-deep MLP >> the
// ~15 wave-loads/CU in flight needed for the 10 B/cyc/CU HBM ceiling.
// ---------------------------------------------------------------------------
__global__ __launch_bounds__(256, 4) void ppo_main(
    const float* __restrict__ mu_new,
    const float* __restrict__ sg_new,
    const float* __restrict__ mu_old,
    const float* __restrict__ sg_old,
    const float* __restrict__ act,
    const float* __restrict__ vnew,
    const float* __restrict__ vold,
    const float* __restrict__ adv,
    const float* __restrict__ ret,
    const float* __restrict__ wgt,
    float* __restrict__ ws,
    int b_rows)
{
    const int t    = threadIdx.x;
    const int wave = t >> 6;        // 4 waves/block
    const int lane = t & 63;
    const int sub  = lane >> 4;     // row within a 4-row set

    float accP = 0.f, accV = 0.f, accE = 0.f, accK = 0.f, accC = 0.f;

    // ---- value-loss pass: one row per thread, coalesced, no divergence ----
    {
        const int r = blockIdx.x * 256 + t;
        if (r < b_rows) {
            const float vn = vnew[r], vo = vold[r], rt = ret[r], w = wgt[r];
            const float vc = vo + fminf(fmaxf(vn - vo, -CLIP_RATIO), CLIP_RATIO);
            const float d1 = rt - vn, d2 = rt - vc;
            accV += fmaxf(d1 * d1, d2 * d2) * w;
        }
    }

    // ---- policy / entropy / kl / clipfrac: 4 rows (1 set) per pipe stage --
    const int n_sets = b_rows >> 2;          // 4 rows per set
    const int stride = gridDim.x << 2;       // total waves
    const int lofs   = lane * 4;
    int s = (blockIdx.x << 2) + wave;

#define PPO_LOAD(P) {                                            \
        const int off = (s << 8) + lofs;                         \
        const int r   = (s << 2) + sub;                          \
        P##mn = *(const float4*)(mu_new + off);                  \
        P##sn = *(const float4*)(sg_new + off);                  \
        P##mo = *(const float4*)(mu_old + off);                  \
        P##so = *(const float4*)(sg_old + off);                  \
        P##a  = *(const float4*)(act    + off);                  \
        P##w  = wgt[r];  P##ad = adv[r];                         \
        s += stride; }

#define PPO_COMPUTE(P) {                                         \
        float en, d;                                             \
        ppo_set(P##mn, P##sn, P##mo, P##so, P##a, en, d);        \
        ppo_tail(en, d, P##w, P##ad, accP, accE, accK, accC); }

    if (s < n_sets) {
        float4 Amn, Asn, Amo, Aso, Aa;  float Aw, Aad;
        float4 Bmn, Bsn, Bmo, Bso, Ba;  float Bw, Bad;

        PPO_LOAD(A);                       // prologue fill
        bool pendA = true;
        while (s < n_sets) {
            PPO_LOAD(B);                   // issue next set's loads...
            PPO_COMPUTE(A);                // ...before consuming current
            pendA = false;
            if (s < n_sets) { PPO_LOAD(A); pendA = true; }
            PPO_COMPUTE(B);
        }
        if (pendA) PPO_COMPUTE(A);
    }
#undef PPO_LOAD
#undef PPO_COMPUTE

    accP *= 0.0625f;   // undo 16x redundancy (exact: power of 2)
    accC *= 0.0625f;

    // full-wave butterfly for all 5 accumulators
#pragma unroll
    for (int m = 1; m < 64; m <<= 1) {
        accP += __shfl_xor(accP, m, 64);
        accV += __shfl_xor(accV, m, 64);
        accE += __shfl_xor(accE, m, 64);
        accK += __shfl_xor(accK, m, 64);
        accC += __shfl_xor(accC, m, 64);
    }

    __shared__ float red[4][5];
    if (lane == 0) {
        red[wave][0] = accP; red[wave][1] = accV; red[wave][2] = accE;
        red[wave][3] = accK; red[wave][4] = accC;
    }
    __syncthreads();

    if (t == 0) {
        float sm[5] = {0.f, 0.f, 0.f, 0.f, 0.f};
#pragma unroll
        for (int wv = 0; wv < 4; ++wv)
#pragma unroll
            for (int k = 0; k < 5; ++k) sm[k] += red[wv][k];
        // column-major so the reduce kernel reads coalesced
#pragma unroll
        for (int k = 0; k < 5; ++k) ws[k * GRID + blockIdx.x] = sm[k];
    }
}

// ---------------------------------------------------------------------------
// Final reduce: 5 waves, one output each — no syncthreads, no atomics.
// ---------------------------------------------------------------------------
__global__ __launch_bounds__(320) void ppo_reduce(
    const float* __restrict__ ws, float* __restrict__ out, int b_rows)
{
    const int wave = threadIdx.x >> 6;   // 0..4 -> output index
    const int lane = threadIdx.x & 63;

    float v = 0.f;
    for (int i = lane; i < GRID; i += 64) v += ws[wave * GRID + i];
#pragma unroll
    for (int m = 1; m < 64; m <<= 1) v += __shfl_xor(v, m, 64);

    if (lane == 0) {
        const float invB = 1.0f / (float)b_rows;
        float o;
        if      (wave == 0) o = -v * invB;        // policy_loss
        else if (wave == 1) o = 0.5f * v * invB;  // value_loss
        else                o = v * invB;         // entropy / kl / clipfrac
        out[wave] = o;
    }
}

extern "C" void kernel_launch(void* const* d_in, const int* in_sizes, int n_in,
                              void* d_out, int out_size, void* d_ws, size_t ws_size,
                              hipStream_t stream) {
    const float* mu_new = (const float*)d_in[0];
    const float* sg_new = (const float*)d_in[1];
    const float* mu_old = (const float*)d_in[2];
    const float* sg_old = (const float*)d_in[3];
    const float* act    = (const float*)d_in[4];
    const float* vnew   = (const float*)d_in[5];
    const float* vold   = (const float*)d_in[6];
    const float* adv    = (const float*)d_in[7];
    const float* ret    = (const float*)d_in[8];
    const float* wgt    = (const float*)d_in[9];
    float* out = (float*)d_out;
    float* ws  = (float*)d_ws;

    const int b_rows = in_sizes[5];     // B from value_new

    ppo_main<<<GRID, 256, 0, stream>>>(mu_new, sg_new, mu_old, sg_old, act,
                                       vnew, vold, adv, ret, wgt,
                                       ws, b_rows);
    ppo_reduce<<<1, 320, 0, stream>>>(ws, out, b_rows);
}